// Round 14
// baseline (134.697 us; speedup 1.0000x reference)
//
#include <hip/hip_runtime.h>
#include <hip/hip_fp16.h>

#define D 64

// ---------------------------------------------------------------------------
// Kernel 1 (fused): blocks [0, nGemmBlocks) compute support = x @ W (fp16 out);
// blocks [nGemmBlocks, ...) build CSR row_ptr from sorted edge_row.
//
// Round-13 change: x-tile staged in LDS as fp16 (16 KB, was 32 KB fp32).
// Block LDS 48->32 KB lifts residency 3->5 blocks/CU (3->5 waves/SIMD).
// x element (row R, k) lives as half2 (k2=k/2) at xs2[R*32 + (k2 ^ M2(R))],
// M2(R) = ((R>>2)&7)<<2: per-read-instruction the 8 rowgroups of a wave hit
// 8 distinct banks (conflict-free); staging writes stay contiguous 8 B.
// ---------------------------------------------------------------------------
__global__ __launch_bounds__(256, 4) void gemm_and_rowptr(
    const float* __restrict__ x, const float* __restrict__ w,
    __half* __restrict__ sup, int N,
    const int* __restrict__ erow, int* __restrict__ rptr, int E,
    int nGemmBlocks) {
  if ((int)blockIdx.x >= nGemmBlocks) {
    const int e = (blockIdx.x - nGemmBlocks) * 256 + threadIdx.x;
    if (e < E) {
      const int r = erow[e];
      const int rprev = (e == 0) ? -1 : erow[e - 1];
      for (int q = rprev + 1; q <= r; ++q) rptr[q] = e;
      if (e == E - 1)
        for (int q = r + 1; q <= N; ++q) rptr[q] = E;
    }
    return;
  }

  __shared__ alignas(16) float ws[D * D];        // 16 KB (W, fp32)
  __shared__ alignas(16) __half2 xs2[128 * 32];  // 16 KB (x tile, fp16, swizzled)
  const int tid = threadIdx.x;
  const int rowBase = blockIdx.x * 128;

  // Stage W: 4096 floats, float4-coalesced, linear.
#pragma unroll
  for (int i = 0; i < 4; ++i) {
    const int idx = i * 1024 + tid * 4;
    *(float4*)&ws[idx] = *(const float4*)&w[idx];
  }
  // Stage x tile (128 rows) as fp16: float4 load -> 2 half2 -> one 8B store.
#pragma unroll
  for (int i = 0; i < 8; ++i) {
    const int idx = i * 1024 + tid * 4;
    const int rl = idx >> 6;  // local row 0..127
    const int c = idx & 63;   // col (multiple of 4)
    const int r = rowBase + rl;
    float4 v = make_float4(0.f, 0.f, 0.f, 0.f);
    if (r < N) v = *(const float4*)&x[(size_t)r * D + c];
    __half2 hp[2];
    hp[0] = __floats2half2_rn(v.x, v.y);
    hp[1] = __floats2half2_rn(v.z, v.w);
    const int M2r = ((rl >> 2) & 7) << 2;
    const int pos = rl * 32 + ((c >> 1) ^ M2r);  // even; 8B-aligned
    *(float2*)&xs2[pos] = *(float2*)hp;
  }
  __syncthreads();

  const int cg = tid & 7;          // col group: cols cg*8 .. cg*8+7
  const int rg = tid >> 3;         // row group: rows rg*4 .. rg*4+3 (0..31)
  const int M2 = (rg & 7) << 2;    // swizzle key (same for the 4 rows)
  const int cb = cg << 3;

  float4 A00 = make_float4(0.f, 0.f, 0.f, 0.f), A01 = A00;
  float4 A10 = A00, A11 = A00, A20 = A00, A21 = A00, A30 = A00, A31 = A00;

#pragma unroll 2
  for (int k2 = 0; k2 < 32; ++k2) {
    const int kk2 = k2 ^ M2;
    const float2 x0 = __half22float2(xs2[(rg * 4 + 0) * 32 + kk2]);
    const float2 x1 = __half22float2(xs2[(rg * 4 + 1) * 32 + kk2]);
    const float2 x2 = __half22float2(xs2[(rg * 4 + 2) * 32 + kk2]);
    const float2 x3 = __half22float2(xs2[(rg * 4 + 3) * 32 + kk2]);
    const int ka = k2 << 1;
    const float4 wa0 = *(const float4*)&ws[ka * D + cb];
    const float4 wa1 = *(const float4*)&ws[ka * D + cb + 4];
    const float4 wb0 = *(const float4*)&ws[(ka + 1) * D + cb];
    const float4 wb1 = *(const float4*)&ws[(ka + 1) * D + cb + 4];
#define FMA_ROW(L, R, xv)                                     \
    L.x = fmaf(wa0.x, xv.x, L.x); L.x = fmaf(wb0.x, xv.y, L.x); \
    L.y = fmaf(wa0.y, xv.x, L.y); L.y = fmaf(wb0.y, xv.y, L.y); \
    L.z = fmaf(wa0.z, xv.x, L.z); L.z = fmaf(wb0.z, xv.y, L.z); \
    L.w = fmaf(wa0.w, xv.x, L.w); L.w = fmaf(wb0.w, xv.y, L.w); \
    R.x = fmaf(wa1.x, xv.x, R.x); R.x = fmaf(wb1.x, xv.y, R.x); \
    R.y = fmaf(wa1.y, xv.x, R.y); R.y = fmaf(wb1.y, xv.y, R.y); \
    R.z = fmaf(wa1.z, xv.x, R.z); R.z = fmaf(wb1.z, xv.y, R.z); \
    R.w = fmaf(wa1.w, xv.x, R.w); R.w = fmaf(wb1.w, xv.y, R.w);
    FMA_ROW(A00, A01, x0)
    FMA_ROW(A10, A11, x1)
    FMA_ROW(A20, A21, x2)
    FMA_ROW(A30, A31, x3)
#undef FMA_ROW
  }

#define STORE_ROW(i, L, R)                                          \
  {                                                                 \
    const int r = rowBase + rg * 4 + (i);                           \
    if (r < N) {                                                    \
      __half2 h[4];                                                 \
      h[0] = __floats2half2_rn((L).x, (L).y);                       \
      h[1] = __floats2half2_rn((L).z, (L).w);                       \
      h[2] = __floats2half2_rn((R).x, (R).y);                       \
      h[3] = __floats2half2_rn((R).z, (R).w);                       \
      *(float4*)&sup[(size_t)r * D + cb] = *(float4*)h;             \
    }                                                               \
  }
  STORE_ROW(0, A00, A01)
  STORE_ROW(1, A10, A11)
  STORE_ROW(2, A20, A21)
  STORE_ROW(3, A30, A31)
#undef STORE_ROW
}

// ---------------------------------------------------------------------------
// Kernel 2: out[r,:] = relu( sum_{e in row r} val[e] * sup[col[e],:] )
// Round-12 version, byte-identical (best measured). One wave per TWO rows,
// software-pipelined metadata + gathers; 8 lanes per edge, float4 gathers;
// 3-level shfl_xor reduce; lanes 0-7 store with fused ReLU.
// ---------------------------------------------------------------------------

#define DECL_ACC(p)                                                   \
  float p##_0 = 0.f, p##_1 = 0.f, p##_2 = 0.f, p##_3 = 0.f,           \
        p##_4 = 0.f, p##_5 = 0.f, p##_6 = 0.f, p##_7 = 0.f;

#define ACCUM(p, Q, V)                                                \
  {                                                                   \
    const __half2* h_ = (const __half2*)&(Q);                         \
    const float2 f0_ = __half22float2(h_[0]);                         \
    const float2 f1_ = __half22float2(h_[1]);                         \
    const float2 f2_ = __half22float2(h_[2]);                         \
    const float2 f3_ = __half22float2(h_[3]);                         \
    p##_0 = fmaf(f0_.x, (V), p##_0); p##_1 = fmaf(f0_.y, (V), p##_1); \
    p##_2 = fmaf(f1_.x, (V), p##_2); p##_3 = fmaf(f1_.y, (V), p##_3); \
    p##_4 = fmaf(f2_.x, (V), p##_4); p##_5 = fmaf(f2_.y, (V), p##_5); \
    p##_6 = fmaf(f3_.x, (V), p##_6); p##_7 = fmaf(f3_.y, (V), p##_7); \
  }

#define REDUCE_STORE(p, r)                                            \
  {                                                                   \
    p##_0 += __shfl_xor(p##_0, 8);  p##_0 += __shfl_xor(p##_0, 16);   \
    p##_0 += __shfl_xor(p##_0, 32);                                   \
    p##_1 += __shfl_xor(p##_1, 8);  p##_1 += __shfl_xor(p##_1, 16);   \
    p##_1 += __shfl_xor(p##_1, 32);                                   \
    p##_2 += __shfl_xor(p##_2, 8);  p##_2 += __shfl_xor(p##_2, 16);   \
    p##_2 += __shfl_xor(p##_2, 32);                                   \
    p##_3 += __shfl_xor(p##_3, 8);  p##_3 += __shfl_xor(p##_3, 16);   \
    p##_3 += __shfl_xor(p##_3, 32);                                   \
    p##_4 += __shfl_xor(p##_4, 8);  p##_4 += __shfl_xor(p##_4, 16);   \
    p##_4 += __shfl_xor(p##_4, 32);                                   \
    p##_5 += __shfl_xor(p##_5, 8);  p##_5 += __shfl_xor(p##_5, 16);   \
    p##_5 += __shfl_xor(p##_5, 32);                                   \
    p##_6 += __shfl_xor(p##_6, 8);  p##_6 += __shfl_xor(p##_6, 16);   \
    p##_6 += __shfl_xor(p##_6, 32);                                   \
    p##_7 += __shfl_xor(p##_7, 8);  p##_7 += __shfl_xor(p##_7, 16);   \
    p##_7 += __shfl_xor(p##_7, 32);                                   \
    if (g == 0) {                                                     \
      float4 o0, o1;                                                  \
      o0.x = fmaxf(p##_0, 0.f); o0.y = fmaxf(p##_1, 0.f);             \
      o0.z = fmaxf(p##_2, 0.f); o0.w = fmaxf(p##_3, 0.f);             \
      o1.x = fmaxf(p##_4, 0.f); o1.y = fmaxf(p##_5, 0.f);             \
      o1.z = fmaxf(p##_6, 0.f); o1.w = fmaxf(p##_7, 0.f);             \
      float* po = &out[(size_t)(r)*D + lg * 8];                       \
      *(float4*)po = o0;                                              \
      *(float4*)(po + 4) = o1;                                        \
    }                                                                 \
  }

#define ROW_GENERAL(r, s, deg, myc, myv)                              \
  {                                                                   \
    DECL_ACC(t)                                                       \
    const int K = (deg) < 64 ? (deg) : 64;                            \
    for (int jb = 0; jb < K; jb += 16) {                              \
      const int j0 = jb + g, j1 = jb + 8 + g;                         \
      int c0 = __shfl((myc), j0); float v0 = __shfl((myv), j0);       \
      int c1 = __shfl((myc), j1); float v1 = __shfl((myv), j1);       \
      if (j0 >= K) { c0 = 0; v0 = 0.f; }                              \
      if (j1 >= K) { c1 = 0; v1 = 0.f; }                              \
      const float4 q0 = sup4[(size_t)c0 * 8 + lg];                    \
      const float4 q1 = sup4[(size_t)c1 * 8 + lg];                    \
      ACCUM(t, q0, v0)                                                \
      ACCUM(t, q1, v1)                                                \
    }                                                                 \
    for (int j = 64; j < (deg); j += 8) {                             \
      int c = 0; float v = 0.f;                                       \
      if (j + g < (deg)) { c = col[(s) + j + g]; v = val[(s) + j + g]; } \
      const float4 q = sup4[(size_t)c * 8 + lg];                      \
      ACCUM(t, q, v)                                                  \
    }                                                                 \
    REDUCE_STORE(t, r)                                                \
  }

__global__ __launch_bounds__(256) void spmm_relu(
    const float4* __restrict__ sup4,  // fp16 rows: 8 float4 per row
    const int* __restrict__ rp, const int* __restrict__ col,
    const float* __restrict__ val, float* __restrict__ out, int N) {
  const int lane = threadIdx.x & 63;
  const int g = lane >> 3;  // edge slot (0..7)
  const int lg = lane & 7;  // column slice: cols 8*lg .. 8*lg+7
  const int r0 = (blockIdx.x * 4 + (threadIdx.x >> 6)) * 2;
  if (r0 >= N) return;
  const int r1 = r0 + 1;
  const bool has1 = r1 < N;

  const int s0 = __builtin_amdgcn_readfirstlane(rp[r0]);
  const int e0 = __builtin_amdgcn_readfirstlane(rp[r0 + 1]);
  int e1 = e0;
  if (has1) e1 = __builtin_amdgcn_readfirstlane(rp[r0 + 2]);
  const int s1 = e0;
  const int deg0 = e0 - s0;
  const int deg1 = e1 - s1;

  // Metadata prefetch for BOTH rows — 4 independent coalesced loads in flight.
  int myc0 = 0, myc1 = 0;
  float myv0 = 0.f, myv1 = 0.f;
  if (lane < deg0) { myc0 = col[s0 + lane]; myv0 = val[s0 + lane]; }
  if (lane < deg1) { myc1 = col[s1 + lane]; myv1 = val[s1 + lane]; }

  if (deg0 <= 16 && deg1 <= 16 && has1) {
    // Fast path (~80% of row pairs): all 4 gather instructions issue
    // back-to-back before any consumption — both rows' misses overlap.
    const int j0 = g, j1 = 8 + g;
    int c00 = __shfl(myc0, j0); float v00 = __shfl(myv0, j0);
    int c01 = __shfl(myc0, j1); float v01 = __shfl(myv0, j1);
    int c10 = __shfl(myc1, j0); float v10 = __shfl(myv1, j0);
    int c11 = __shfl(myc1, j1); float v11 = __shfl(myv1, j1);
    if (j0 >= deg0) { c00 = 0; v00 = 0.f; }
    if (j1 >= deg0) { c01 = 0; v01 = 0.f; }
    if (j0 >= deg1) { c10 = 0; v10 = 0.f; }
    if (j1 >= deg1) { c11 = 0; v11 = 0.f; }
    const float4 q00 = sup4[(size_t)c00 * 8 + lg];
    const float4 q01 = sup4[(size_t)c01 * 8 + lg];
    const float4 q10 = sup4[(size_t)c10 * 8 + lg];
    const float4 q11 = sup4[(size_t)c11 * 8 + lg];
    {
      DECL_ACC(a)
      ACCUM(a, q00, v00)
      ACCUM(a, q01, v01)
      REDUCE_STORE(a, r0)
    }
    {
      DECL_ACC(b)
      ACCUM(b, q10, v10)
      ACCUM(b, q11, v11)
      REDUCE_STORE(b, r1)
    }
    return;
  }

  // General path: rows processed sequentially.
  ROW_GENERAL(r0, s0, deg0, myc0, myv0)
  if (has1) ROW_GENERAL(r1, s1, deg1, myc1, myv1)
}

#undef ROW_GENERAL
#undef REDUCE_STORE
#undef ACCUM
#undef DECL_ACC

// ---------------------------------------------------------------------------
extern "C" void kernel_launch(void* const* d_in, const int* in_sizes, int n_in,
                              void* d_out, int out_size, void* d_ws, size_t ws_size,
                              hipStream_t stream) {
  const float* x = (const float*)d_in[0];
  const float* w = (const float*)d_in[1];
  const int* erow = (const int*)d_in[2];
  const int* ecol = (const int*)d_in[3];
  const float* eval = (const float*)d_in[4];
  float* out = (float*)d_out;

  const int N = in_sizes[0] / D;  // 100000
  const int E = in_sizes[2];      // 1200000

  __half* sup = (__half*)d_ws;  // N*64 fp16 = 12.8 MB
  int* rp = (int*)((char*)d_ws + (((size_t)N * D * sizeof(__half) + 255) & ~(size_t)255));

  const int nGemmBlocks = (N + 127) / 128;
  const int nRpBlocks = (E + 255) / 256;

  gemm_and_rowptr<<<nGemmBlocks + nRpBlocks, 256, 0, stream>>>(
      x, w, sup, N, erow, rp, E, nGemmBlocks);
  spmm_relu<<<(N + 7) / 8, 256, 0, stream>>>((const float4*)sup, rp, ecol, eval,
                                             out, N);
}